// Round 10
// baseline (100.982 us; speedup 1.0000x reference)
//
#include <hip/hip_runtime.h>

#define B_ 256
#define N_IN 1152
#define N_OUT 10
#define OJ 160                     // N_OUT * D_OUT
#define SN (B_*OJ)                 // 40960
#define LOG2E 1.44269504088896340736f
#define NPB 8                      // n's per block
#define NPW 2                      // n's per wave (4 waves/block)
#define NSG (N_IN/NPB)             // 144 partial groups

typedef __attribute__((ext_vector_type(8))) short bf16x8;
typedef __attribute__((ext_vector_type(4))) float f32x4;

#define NW_ELEMS (N_IN*N_OUT*16)   // 184320 rows of 8 (W)
#define NX_ELEMS (B_*N_IN)         // 294912 rows of 8 (x)
#define NWB (NW_ELEMS/256)         // 720 W-pack blocks
#define NTILES ((N_IN/16)*(B_/16)) // 1152 x-transpose tiles

// ---- bf16 split helpers (RNE) ----
__device__ __forceinline__ unsigned short f2bf(float f) {
  unsigned u = __float_as_uint(f);
  u += 0x7fffu + ((u >> 16) & 1u);
  return (unsigned short)(u >> 16);
}
__device__ __forceinline__ float bf2f(unsigned short s) {
  return __uint_as_float(((unsigned)s) << 16);
}
__device__ __forceinline__ void split8(const float* p, bf16x8& vh, bf16x8& vl) {
  const float4 a = *(const float4*)p;
  const float4 b = *(const float4*)(p + 4);
  const float w[8] = {a.x,a.y,a.z,a.w,b.x,b.y,b.z,b.w};
#pragma unroll
  for (int e=0;e<8;e++){
    unsigned short hh = f2bf(w[e]);
    vh[e] = (short)hh;
    vl[e] = (short)f2bf(w[e] - bf2f(hh));
  }
}

// ---- DPP rotate-reduce over a 16-lane row ----
template<int CTRL>
__device__ __forceinline__ float dpp_add(float xx) {
  int y = __builtin_amdgcn_mov_dpp(__float_as_int(xx), CTRL, 0xF, 0xF, false);
  return xx + __int_as_float(y);
}
__device__ __forceinline__ float row_sum16(float xx) {
  xx = dpp_add<0x128>(xx); xx = dpp_add<0x124>(xx);
  xx = dpp_add<0x122>(xx); xx = dpp_add<0x121>(xx);
  return xx;
}
__device__ __forceinline__ float squash_elem(float t) {
  const float sq = row_sum16(t * t);
  return t * (sq / (1.f + sq)) * rsqrtf(sq + 1e-8f);
}

// ---- pack: W linear; x via LDS-transposed 16x16 tiles -> [n][b] ----
__global__ __launch_bounds__(256) void pack_all(const float* __restrict__ W,
                                                const float* __restrict__ x,
                                                short* __restrict__ WH, short* __restrict__ WL,
                                                short* __restrict__ XH, short* __restrict__ XL) {
  const int bid = blockIdx.x, tid = threadIdx.x;
  if (bid < NWB) {
    const int t = bid*256 + tid;
    bf16x8 vh, vl; split8(W + (size_t)t*8, vh, vl);
    ((bf16x8*)WH)[t] = vh; ((bf16x8*)WL)[t] = vl;
  } else {
    __shared__ bf16x8 TH[16*17], TL[16*17];
    const int tile = bid - NWB;
    const int nt = tile >> 4, bt = tile & 15;
    const int nn = tid & 15, bb = tid >> 4;        // n fastest: coalesced reads
    bf16x8 vh, vl;
    split8(x + ((size_t)(bt*16+bb)*N_IN + nt*16+nn)*8, vh, vl);
    TH[nn*17 + bb] = vh; TL[nn*17 + bb] = vl;
    __syncthreads();
    const int bb2 = tid & 15, nn2 = tid >> 4;      // b fastest: coalesced writes
    const size_t o = (size_t)(nt*16+nn2)*B_ + bt*16 + bb2;
    ((bf16x8*)XH)[o] = TH[nn2*17 + bb2];
    ((bf16x8*)XL)[o] = TL[nn2*17 + bb2];
  }
}

// K-chunk trick: one 16x16x32 MFMA; lane's K-chunk c=l>>4 pulls A from
// [WH,WL,WH,WL] and B from [XH,XH,XL,XL] => exact (Wh+Wl)(xh+xl).
// C layout: col=lane&15=b, row=c*4+e=j.

// ---- two-stage 4-wave LDS tree (20 KB -> 8 blocks/CU) + P write ----
__device__ __forceinline__ void tree_and_store(f32x4 (&acc)[N_OUT],
                                               f32x4 (*red)[640],
                                               int w, int l, int sg, int b0,
                                               int bb, int c,
                                               float* __restrict__ P) {
  if (w >= 2) {
#pragma unroll
    for (int o=0;o<N_OUT;o++) red[w-2][o*64 + l] = acc[o];
  }
  __syncthreads();
  if (w < 2) {
#pragma unroll
    for (int o=0;o<N_OUT;o++) acc[o] += red[w][o*64 + l];
  }
  __syncthreads();
  if (w == 1) {
#pragma unroll
    for (int o=0;o<N_OUT;o++) red[0][o*64 + l] = acc[o];
  }
  __syncthreads();
  if (w == 0) {
    float* Pp = &P[(size_t)sg*SN + (size_t)(b0+bb)*OJ + c*4];
#pragma unroll
    for (int o=0;o<N_OUT;o++) {
      acc[o] += red[0][o*64 + l];
      *(f32x4*)&Pp[o*16] = acc[o];
    }
  }
}

// ---- pass 1: uniform coupling (0.1 folded into finish) ----
__global__ __launch_bounds__(256) void caps_pass1(
    const short* __restrict__ WH, const short* __restrict__ WL,
    const short* __restrict__ XH, const short* __restrict__ XL,
    float* __restrict__ P) {
  __shared__ f32x4 red[2][640];                    // 20 KB
  const int tid = threadIdx.x, w = tid >> 6, l = tid & 63;
  const int bb = l & 15, c = l >> 4;
  const int sg = blockIdx.x, bg = blockIdx.y;
  const int b0 = bg*16;
  const int n0 = sg*NPB + w*NPW;
  const short* Abase = (c & 1)  ? WL : WH;
  const short* Bbase = (c >> 1) ? XL : XH;

  const f32x4 zz = {0.f,0.f,0.f,0.f};
  f32x4 acc[N_OUT];
#pragma unroll
  for (int o=0;o<N_OUT;o++) acc[o] = zz;

#pragma unroll
  for (int nn=0; nn<NPW; ++nn) {
    const int n = n0 + nn;
    const bf16x8 bfrag = *(const bf16x8*)&Bbase[((size_t)n*B_ + b0 + bb)*8];
    const short* Ap = &Abase[(size_t)n*1280 + bb*8];
#pragma unroll
    for (int o=0;o<N_OUT;o++) {
      const bf16x8 afrag = *(const bf16x8*)&Ap[o*128];
      acc[o] = __builtin_amdgcn_mfma_f32_16x16x32_bf16(afrag, bfrag, acc[o], 0,0,0);
    }
  }
  tree_and_store(acc, red, w, l, sg, b0, bb, c, P);
}

// ---- pass 2/3: u via MFMA; logits = u.veff (log2 domain); softmax; partial ----
__global__ __launch_bounds__(256) void caps_pass23(
    const short* __restrict__ WH, const short* __restrict__ WL,
    const short* __restrict__ XH, const short* __restrict__ XL,
    const float* __restrict__ veff, float* __restrict__ P) {
  __shared__ f32x4 red[2][640];                    // 20 KB
  const int tid = threadIdx.x, w = tid >> 6, l = tid & 63;
  const int bb = l & 15, c = l >> 4;
  const int sg = blockIdx.x, bg = blockIdx.y;
  const int b0 = bg*16;
  const int n0 = sg*NPB + w*NPW;
  const short* Abase = (c & 1)  ? WL : WH;
  const short* Bbase = (c >> 1) ? XL : XH;

  const f32x4 zz = {0.f,0.f,0.f,0.f};
  f32x4 acc[N_OUT], vj[N_OUT];
  const float* vp = &veff[(size_t)(b0+bb)*OJ + c*4];
#pragma unroll
  for (int o=0;o<N_OUT;o++) { vj[o] = *(const f32x4*)&vp[o*16]; acc[o] = zz; }

#pragma unroll
  for (int nn=0; nn<NPW; ++nn) {
    const int n = n0 + nn;
    const bf16x8 bfrag = *(const bf16x8*)&Bbase[((size_t)n*B_ + b0 + bb)*8];
    const short* Ap = &Abase[(size_t)n*1280 + bb*8];
    f32x4 u[N_OUT];
#pragma unroll
    for (int o=0;o<N_OUT;o++) {
      const bf16x8 afrag = *(const bf16x8*)&Ap[o*128];
      u[o] = __builtin_amdgcn_mfma_f32_16x16x32_bf16(afrag, bfrag, zz, 0,0,0);
    }
    float ez[N_OUT], Z = 0.f;
#pragma unroll
    for (int o=0;o<N_OUT;o++) {
      float t = u[o][0]*vj[o][0] + u[o][1]*vj[o][1]
              + u[o][2]*vj[o][2] + u[o][3]*vj[o][3];
      t += __shfl_xor(t, 16);
      t += __shfl_xor(t, 32);
      ez[o] = exp2f(t);                            // veff stored in log2 domain
      Z += ez[o];
    }
    const float invZ = 1.f / Z;
#pragma unroll
    for (int o=0;o<N_OUT;o++) acc[o] += (ez[o]*invZ) * u[o];
  }
  tree_and_store(acc, red, w, l, sg, b0, bb, c, P);
}

// ---- reduce partials over NSG + squash (+ optional vprev, output scaling) ----
__global__ __launch_bounds__(256) void caps_finish(const float* __restrict__ P, float scale,
                                                   const float* __restrict__ vprev,
                                                   float* __restrict__ vout, float lscale) {
  const int idx = blockIdx.x*256 + threadIdx.x;      // b*160 + o*16 + j
  float t = 0.f;
#pragma unroll 8
  for (int g=0; g<NSG; ++g) t += P[(size_t)g*SN + idx];
  t *= scale;
  float v = squash_elem(t) * lscale;
  if (vprev != nullptr) v += vprev[idx];
  vout[idx] = v;
}

extern "C" void kernel_launch(void* const* d_in, const int* in_sizes, int n_in,
                              void* d_out, int out_size, void* d_ws, size_t ws_size,
                              hipStream_t stream) {
  const float* x = (const float*)d_in[0];   // (256,1152,8)
  const float* W = (const float*)d_in[1];   // (1,1152,10,16,8)
  float* out = (float*)d_out;               // (256,10,16)

  float* P   = (float*)d_ws;                // NSG*SN floats = 23.6 MB (ws ~256 MB)
  float* v1  = P  + (size_t)NSG*SN;         // stored * log2e
  float* v12 = v1 + SN;                     // stored * log2e
  short* WH = (short*)(v12 + SN);
  short* WL = WH + (size_t)NW_ELEMS*8;
  short* XH = WL + (size_t)NW_ELEMS*8;
  short* XL = XH + (size_t)NX_ELEMS*8;      // total ws ~= 39 MB

  pack_all<<<NWB + NTILES, 256, 0, stream>>>(W, x, WH, WL, XH, XL);

  const dim3 pg(NSG, 16), pb(256);

  // iter 1: uniform c -> P ; v1 = squash(0.1*s1)*log2e
  caps_pass1<<<pg, pb, 0, stream>>>(WH, WL, XH, XL, P);
  caps_finish<<<SN/256, 256, 0, stream>>>(P, 0.1f, nullptr, v1, LOG2E);

  // iter 2: logits = u.v1 -> P ; v12 = v1 + squash(s2)*log2e
  caps_pass23<<<pg, pb, 0, stream>>>(WH, WL, XH, XL, v1, P);
  caps_finish<<<SN/256, 256, 0, stream>>>(P, 1.0f, v1, v12, LOG2E);

  // iter 3: logits = u.v12 -> P ; out = squash(s3)
  caps_pass23<<<pg, pb, 0, stream>>>(WH, WL, XH, XL, v12, P);
  caps_finish<<<SN/256, 256, 0, stream>>>(P, 1.0f, nullptr, out, 1.0f);
}

// Round 11
// 85.918 us; speedup vs baseline: 1.1753x; 1.1753x over previous
//
#include <hip/hip_runtime.h>

#define B_ 256
#define N_IN 1152
#define N_OUT 10
#define D_OUT 16
#define OJ 160                     // N_OUT * D_OUT
#define SN (B_*OJ)                 // 40960
#define LOG2E 1.44269504088896340736f
#define NPB 16                     // n's per block
#define NPW 4                      // n's per wave (4 waves/block)
#define NSG (N_IN/NPB)             // 72 partial groups  (P = 11.8 MB, ~1.4 MB/XCD: L2-fit)

typedef __attribute__((ext_vector_type(8))) short bf16x8;
typedef __attribute__((ext_vector_type(4))) float f32x4;

#define NW_ELEMS (N_IN*N_OUT*D_OUT)      // 184320 rows of 8 (W)
#define NX_ELEMS (B_*N_IN)               // 294912 rows of 8 (x)
#define NWB (NW_ELEMS/256)               // 720 W-pack blocks
#define NTILES ((N_IN/16)*(B_/16))       // 1152 x-transpose tiles

// ---- bf16 split helpers (RNE) ----
__device__ __forceinline__ unsigned short f2bf(float f) {
  unsigned u = __float_as_uint(f);
  u += 0x7fffu + ((u >> 16) & 1u);
  return (unsigned short)(u >> 16);
}
__device__ __forceinline__ float bf2f(unsigned short s) {
  return __uint_as_float(((unsigned)s) << 16);
}
__device__ __forceinline__ void split8(const float* p, bf16x8& vh, bf16x8& vl) {
  const float4 a = *(const float4*)p;
  const float4 b = *(const float4*)(p + 4);
  const float w[8] = {a.x,a.y,a.z,a.w,b.x,b.y,b.z,b.w};
#pragma unroll
  for (int e=0;e<8;e++){
    unsigned short hh = f2bf(w[e]);
    vh[e] = (short)hh;
    vl[e] = (short)f2bf(w[e] - bf2f(hh));
  }
}

// ---- DPP rotate-reduce over a 16-lane row ----
template<int CTRL>
__device__ __forceinline__ float dpp_add(float xx) {
  int y = __builtin_amdgcn_mov_dpp(__float_as_int(xx), CTRL, 0xF, 0xF, false);
  return xx + __int_as_float(y);
}
__device__ __forceinline__ float row_sum16(float xx) {
  xx = dpp_add<0x128>(xx); xx = dpp_add<0x124>(xx);
  xx = dpp_add<0x122>(xx); xx = dpp_add<0x121>(xx);
  return xx;
}
__device__ __forceinline__ float squash_elem(float t) {
  const float sq = row_sum16(t * t);
  return t * (sq / (1.f + sq)) * rsqrtf(sq + 1e-8f);
}

// ---- pack: W linear; x via LDS-transposed 16x16 tiles -> [n][b] ----
__global__ __launch_bounds__(256) void pack_all(const float* __restrict__ W,
                                                const float* __restrict__ x,
                                                short* __restrict__ WH, short* __restrict__ WL,
                                                short* __restrict__ XH, short* __restrict__ XL) {
  const int bid = blockIdx.x, tid = threadIdx.x;
  if (bid < NWB) {
    const int t = bid*256 + tid;
    bf16x8 vh, vl; split8(W + (size_t)t*8, vh, vl);
    ((bf16x8*)WH)[t] = vh; ((bf16x8*)WL)[t] = vl;
  } else {
    __shared__ bf16x8 TH[16*17], TL[16*17];
    const int tile = bid - NWB;
    const int nt = tile >> 4, bt = tile & 15;
    const int nn = tid & 15, bb = tid >> 4;        // n fastest: coalesced reads
    bf16x8 vh, vl;
    split8(x + ((size_t)(bt*16+bb)*N_IN + nt*16+nn)*8, vh, vl);
    TH[nn*17 + bb] = vh; TL[nn*17 + bb] = vl;
    __syncthreads();
    const int bb2 = tid & 15, nn2 = tid >> 4;      // b fastest: coalesced writes
    const size_t o = (size_t)(nt*16+nn2)*B_ + bt*16 + bb2;
    ((bf16x8*)XH)[o] = TH[nn2*17 + bb2];
    ((bf16x8*)XL)[o] = TL[nn2*17 + bb2];
  }
}

// K-chunk trick: one 16x16x32 MFMA; lane's K-chunk c=l>>4 pulls A from
// [WH,WL,WH,WL] and B from [XH,XH,XL,XL] => exact (Wh+Wl)(xh+xl).
// C layout: col=lane&15=b, row=c*4+e=j.

// ---- pass 1: uniform coupling (0.1 folded into finish) ----
__global__ __launch_bounds__(256) void caps_pass1(const short* __restrict__ WH,
                                                  const short* __restrict__ WL,
                                                  const short* __restrict__ XH,
                                                  const short* __restrict__ XL,
                                                  float* __restrict__ P) {
  __shared__ f32x4 red[3*640];         // 30 KB; red[(w-1)*640 + o*64 + l]:
                                       // lane-contiguous 16B slots -> all 32 banks, conflict-free
  const int tid = threadIdx.x, w = tid >> 6, l = tid & 63;
  const int bb = l & 15, c = l >> 4;
  const int b0 = blockIdx.y * 16;
  const int n0 = blockIdx.x * NPB + w * NPW;
  const short* Abase = (c & 1)  ? WL : WH;
  const short* Bbase = (c >> 1) ? XL : XH;

  f32x4 acc[N_OUT];
  const f32x4 zz = {0.f,0.f,0.f,0.f};
#pragma unroll
  for (int o=0;o<N_OUT;o++) acc[o] = zz;

  for (int nn=0; nn<NPW; ++nn) {
    const int n = n0 + nn;
    const bf16x8 bfrag = *(const bf16x8*)&Bbase[((size_t)n*B_ + b0 + bb)*8];
    const short* Ap = &Abase[(size_t)n*1280 + bb*8];
#pragma unroll
    for (int o=0;o<N_OUT;o++) {
      const bf16x8 afrag = *(const bf16x8*)&Ap[o*128];
      acc[o] = __builtin_amdgcn_mfma_f32_16x16x32_bf16(afrag, bfrag, acc[o], 0,0,0);
    }
  }

  if (w) {
#pragma unroll
    for (int o=0;o<N_OUT;o++) red[(w-1)*640 + o*64 + l] = acc[o];
  }
  __syncthreads();
  if (!w) {
    float* Pp = &P[((size_t)blockIdx.x*B_ + b0 + bb)*OJ + c*4];
#pragma unroll
    for (int o=0;o<N_OUT;o++) {
      acc[o] += red[o*64+l] + red[640+o*64+l] + red[1280+o*64+l];
      *(f32x4*)&Pp[o*16] = acc[o];
    }
  }
}

// ---- pass 2/3: u via MFMA, logits = u.veff (log2 domain), softmax, partial ----
__global__ __launch_bounds__(256) void caps_pass23(const short* __restrict__ WH,
                                                   const short* __restrict__ WL,
                                                   const short* __restrict__ XH,
                                                   const short* __restrict__ XL,
                                                   const float* __restrict__ veff,
                                                   float* __restrict__ P) {
  __shared__ f32x4 red[3*640];         // 30 KB, conflict-free layout
  const int tid = threadIdx.x, w = tid >> 6, l = tid & 63;
  const int bb = l & 15, c = l >> 4;
  const int b0 = blockIdx.y * 16;
  const int n0 = blockIdx.x * NPB + w * NPW;
  const short* Abase = (c & 1)  ? WL : WH;
  const short* Bbase = (c >> 1) ? XL : XH;

  f32x4 vj[N_OUT], acc[N_OUT];
  const f32x4 zz = {0.f,0.f,0.f,0.f};
  const float* vp = &veff[(size_t)(b0+bb)*OJ + c*4];
#pragma unroll
  for (int o=0;o<N_OUT;o++) { vj[o] = *(const f32x4*)&vp[o*16]; acc[o] = zz; }

  for (int nn=0; nn<NPW; ++nn) {
    const int n = n0 + nn;
    const bf16x8 bfrag = *(const bf16x8*)&Bbase[((size_t)n*B_ + b0 + bb)*8];
    const short* Ap = &Abase[(size_t)n*1280 + bb*8];
    f32x4 u[N_OUT];
#pragma unroll
    for (int o=0;o<N_OUT;o++) {
      const bf16x8 afrag = *(const bf16x8*)&Ap[o*128];
      u[o] = __builtin_amdgcn_mfma_f32_16x16x32_bf16(afrag, bfrag, zz, 0,0,0);
    }
    float ez[N_OUT], Z = 0.f;
#pragma unroll
    for (int o=0;o<N_OUT;o++) {
      float t = u[o][0]*vj[o][0] + u[o][1]*vj[o][1]
              + u[o][2]*vj[o][2] + u[o][3]*vj[o][3];
      t += __shfl_xor(t, 16);
      t += __shfl_xor(t, 32);
      ez[o] = exp2f(t);                // veff already in log2 domain
      Z += ez[o];
    }
    const float invZ = __builtin_amdgcn_rcpf(Z);   // approx rcp: ~1e-7 rel, saves div-fixup
#pragma unroll
    for (int o=0;o<N_OUT;o++) acc[o] += (ez[o] * invZ) * u[o];
  }

  if (w) {
#pragma unroll
    for (int o=0;o<N_OUT;o++) red[(w-1)*640 + o*64 + l] = acc[o];
  }
  __syncthreads();
  if (!w) {
    float* Pp = &P[((size_t)blockIdx.x*B_ + b0 + bb)*OJ + c*4];
#pragma unroll
    for (int o=0;o<N_OUT;o++) {
      acc[o] += red[o*64+l] + red[640+o*64+l] + red[1280+o*64+l];
      *(f32x4*)&Pp[o*16] = acc[o];
    }
  }
}

// ---- reduce partials over NSG + squash (+ optional vprev, output scaling) ----
__global__ __launch_bounds__(256) void caps_finish(const float* __restrict__ P, float scale,
                                                   const float* __restrict__ vprev,
                                                   float* __restrict__ vout, float lscale) {
  const int idx = blockIdx.x*256 + threadIdx.x;      // b*160 + o*16 + j
  float t = 0.f;
#pragma unroll 8
  for (int g=0; g<NSG; ++g) t += P[(size_t)g*SN + idx];
  t *= scale;
  float v = squash_elem(t) * lscale;
  if (vprev != nullptr) v += vprev[idx];
  vout[idx] = v;
}

extern "C" void kernel_launch(void* const* d_in, const int* in_sizes, int n_in,
                              void* d_out, int out_size, void* d_ws, size_t ws_size,
                              hipStream_t stream) {
  const float* x = (const float*)d_in[0];   // (256,1152,8)
  const float* W = (const float*)d_in[1];   // (1,1152,10,16,8)
  float* out = (float*)d_out;               // (256,10,16)

  float* P   = (float*)d_ws;                // NSG*SN floats = 11.8 MB
  float* v1  = P  + (size_t)NSG*SN;         // stored * log2e
  float* v12 = v1 + SN;                     // stored * log2e
  short* WH = (short*)(v12 + SN);
  short* WL = WH + (size_t)NW_ELEMS*8;
  short* XH = WL + (size_t)NW_ELEMS*8;
  short* XL = XH + (size_t)NX_ELEMS*8;      // total ws ~= 27.5 MB

  pack_all<<<NWB + NTILES, 256, 0, stream>>>(W, x, WH, WL, XH, XL);

  const dim3 pg(NSG, 16), pb(256);

  // iter 1: uniform c -> P ; v1 = squash(0.1*s1)*log2e
  caps_pass1<<<pg, pb, 0, stream>>>(WH, WL, XH, XL, P);
  caps_finish<<<SN/256, 256, 0, stream>>>(P, 0.1f, nullptr, v1, LOG2E);

  // iter 2: logits = u.v1 -> P ; v12 = v1 + squash(s2)*log2e
  caps_pass23<<<pg, pb, 0, stream>>>(WH, WL, XH, XL, v1, P);
  caps_finish<<<SN/256, 256, 0, stream>>>(P, 1.0f, v1, v12, LOG2E);

  // iter 3: logits = u.v12 -> P ; out = squash(s3)
  caps_pass23<<<pg, pb, 0, stream>>>(WH, WL, XH, XL, v12, P);
  caps_finish<<<SN/256, 256, 0, stream>>>(P, 1.0f, nullptr, out, 1.0f);
}